// Round 14
// baseline (26.591 us; speedup 1.0000x reference)
//
#include <hip/hip_runtime.h>
#include <math.h>

#define BLOCK 1024
#define EPB 240       // batch elements per block (waves 0-14)
#define TAPS 16
#define HWIN 16       // halo window: 16 elems handled by wave 15 (15 used + 1 pad)

typedef float f32x4 __attribute__((ext_vector_type(4)));
typedef float f32x2 __attribute__((ext_vector_type(2)));

__device__ __forceinline__ float eluf(float v) { return v > 0.f ? v : expm1f(v); }
__device__ __forceinline__ float dot4v(f32x4 a, f32x4 b) {
    return a[0] * b[0] + a[1] * b[1] + a[2] * b[2] + a[3] * b[3];
}

// Cooperative 4-lane conv1+conv2 for batch element ge (must be valid).
// Lane role j = t&3; iteration p loads float4 #(4p+j) so the element's 4 lanes
// cover one contiguous 64B line. All x reads are NON-TEMPORAL (no reuse):
// reduces L2/L3 allocation + tag pressure on the streaming read path.
__device__ __forceinline__ void conv_elem(const f32x4* __restrict__ xf4, long ge,
        int j, f32x4 wv0, f32x4 wv1, float b1s,
        const float* __restrict__ w2, float b20, float b21,
        float& sr, float& si)
{
    const f32x4* base = xf4 + ge * 32;
    f32x4 v0 = __builtin_nontemporal_load(base + j);
    f32x4 v1 = __builtin_nontemporal_load(base + 4 + j);
    f32x4 v2 = __builtin_nontemporal_load(base + 8 + j);
    f32x4 v3 = __builtin_nontemporal_load(base + 12 + j);
    float a0 = dot4v(v0, wv0), a1 = dot4v(v1, wv0),
          a2 = dot4v(v2, wv0), a3 = dot4v(v3, wv0);
    v0 = __builtin_nontemporal_load(base + 16 + j);
    v1 = __builtin_nontemporal_load(base + 20 + j);
    v2 = __builtin_nontemporal_load(base + 24 + j);
    v3 = __builtin_nontemporal_load(base + 28 + j);
    a0 += dot4v(v0, wv1); a1 += dot4v(v1, wv1);
    a2 += dot4v(v2, wv1); a3 += dot4v(v3, wv1);

    // 4-lane butterfly: every lane ends with the full h sums
    a0 += __shfl_xor(a0, 1); a1 += __shfl_xor(a1, 1);
    a2 += __shfl_xor(a2, 1); a3 += __shfl_xor(a3, 1);
    a0 += __shfl_xor(a0, 2); a1 += __shfl_xor(a1, 2);
    a2 += __shfl_xor(a2, 2); a3 += __shfl_xor(a3, 2);

    float h0 = eluf(a0 + b1s), h1 = eluf(a1 + b1s);
    float h2 = eluf(a2 + b1s), h3 = eluf(a3 + b1s);

    float pr = b20 + h0 * w2[0] + h1 * w2[1] + h2 * w2[2] + h3 * w2[3];
    float pi = b21 + h0 * w2[4] + h1 * w2[5] + h2 * w2[6] + h3 * w2[7];
    sr = eluf(pr);
    si = eluf(pi);
}

__global__ __launch_bounds__(BLOCK, 8) void NF_20581483282566_kernel(
    const float* __restrict__ x,
    const float* __restrict__ w1, const float* __restrict__ b1,
    const float* __restrict__ w2, const float* __restrict__ b2,
    const float* __restrict__ tr, const float* __restrict__ ti,
    float2* __restrict__ out, int B)
{
    __shared__ float s_r[HWIN + EPB];
    __shared__ float s_i[HWIN + EPB];

    const int t = threadIdx.x;
    const int j = t & 3;
    const long b0 = (long)blockIdx.x * EPB;

    const f32x4* xf4 = reinterpret_cast<const f32x4*>(x);
    const f32x4* w1v = reinterpret_cast<const f32x4*>(w1);
    const f32x4 wv0 = w1v[j];        // c=0 weights for this lane role
    const f32x4 wv1 = w1v[4 + j];    // c=1
    const float b1s = b1[0];
    const float b20 = b2[0], b21 = b2[1];

    if (t < 4 * EPB) {
        // ---- main elements: waves 0-14, 4 lanes per element ----
        const int e_loc = t >> 2;             // 0..239
        const long ge = b0 + e_loc;
        if (ge < B) {
            float sr, si;
            conv_elem(xf4, ge, j, wv0, wv1, b1s, w2, b20, b21, sr, si);
            if (j == 0) { s_r[HWIN + e_loc] = sr; s_i[HWIN + e_loc] = si; }
        }
    } else {
        // ---- halo: wave 15 (16 elements), loads issued concurrently ----
        const int eh = (t - 4 * EPB) >> 2;    // 0..15
        const long he = b0 - HWIN + eh;
        float sr = 0.f, si = 0.f;
        if (he >= 0)
            conv_elem(xf4, he, j, wv0, wv1, b1s, w2, b20, b21, sr, si);
        if (j == 0) { s_r[eh] = sr; s_i[eh] = si; }
    }
    __syncthreads();

    // ---- 16-tap complex FIR along the batch axis ----
    if (t < EPB) {
        const long b = b0 + t;
        if (b < B) {
            float yr = 0.f, yi = 0.f;
#pragma unroll
            for (int jj = 0; jj < TAPS; ++jj) {
                float a = s_r[HWIN + t - jj];
                float c = s_i[HWIN + t - jj];
                float trj = tr[jj], tij = ti[jj];
                yr += a * trj - c * tij;
                yi += a * tij + c * trj;
            }
            f32x2 y; y[0] = yr; y[1] = yi;
            __builtin_nontemporal_store(y, reinterpret_cast<f32x2*>(out) + b);
        }
    }
}

extern "C" void kernel_launch(void* const* d_in, const int* in_sizes, int n_in,
                              void* d_out, int out_size, void* d_ws, size_t ws_size,
                              hipStream_t stream) {
    const float* x  = (const float*)d_in[0];
    const float* w1 = (const float*)d_in[1];
    const float* b1 = (const float*)d_in[2];
    const float* w2 = (const float*)d_in[3];
    const float* b2 = (const float*)d_in[4];
    const float* tr = (const float*)d_in[5];
    const float* ti = (const float*)d_in[6];
    float2* out = (float2*)d_out;

    const int B = in_sizes[0] / 128;   // x is (B, 2, 64)
    const int grid = (B + EPB - 1) / EPB;
    NF_20581483282566_kernel<<<grid, BLOCK, 0, stream>>>(x, w1, b1, w2, b2, tr, ti, out, B);
}

// Round 15
// 23.959 us; speedup vs baseline: 1.1099x; 1.1099x over previous
//
#include <hip/hip_runtime.h>
#include <math.h>

#define BLOCK 1024
#define EPB 240       // batch elements per block (waves 0-14)
#define TAPS 16
#define HWIN 16       // halo window: 16 elems handled by wave 15 (15 used + 1 pad)

__device__ __forceinline__ float eluf(float v) { return v > 0.f ? v : expm1f(v); }
__device__ __forceinline__ float dot4(float4 a, float4 b) {
    return a.x * b.x + a.y * b.y + a.z * b.z + a.w * b.w;
}

// Cooperative 4-lane conv1+conv2 for batch element ge (must be valid).
// Lane role j = t&3; iteration p loads float4 #(4p+j) so the element's 4 lanes
// cover one contiguous 64B line -> wave instr touches 16 full lines.
// Loads in 2 batches of 4 to keep live data regs small.
__device__ __forceinline__ void conv_elem(const float4* __restrict__ xf4, long ge,
        int j, float4 wv0, float4 wv1, float b1s,
        const float* __restrict__ w2, float b20, float b21,
        float& sr, float& si)
{
    const float4* base = xf4 + ge * 32;
    float4 v0 = base[j],      v1 = base[4 + j],
           v2 = base[8 + j],  v3 = base[12 + j];
    float a0 = dot4(v0, wv0), a1 = dot4(v1, wv0),
          a2 = dot4(v2, wv0), a3 = dot4(v3, wv0);
    v0 = base[16 + j]; v1 = base[20 + j]; v2 = base[24 + j]; v3 = base[28 + j];
    a0 += dot4(v0, wv1); a1 += dot4(v1, wv1);
    a2 += dot4(v2, wv1); a3 += dot4(v3, wv1);

    // 4-lane butterfly: every lane ends with the full h sums
    a0 += __shfl_xor(a0, 1); a1 += __shfl_xor(a1, 1);
    a2 += __shfl_xor(a2, 1); a3 += __shfl_xor(a3, 1);
    a0 += __shfl_xor(a0, 2); a1 += __shfl_xor(a1, 2);
    a2 += __shfl_xor(a2, 2); a3 += __shfl_xor(a3, 2);

    float h0 = eluf(a0 + b1s), h1 = eluf(a1 + b1s);
    float h2 = eluf(a2 + b1s), h3 = eluf(a3 + b1s);

    float pr = b20 + h0 * w2[0] + h1 * w2[1] + h2 * w2[2] + h3 * w2[3];
    float pi = b21 + h0 * w2[4] + h1 * w2[5] + h2 * w2[6] + h3 * w2[7];
    sr = eluf(pr);
    si = eluf(pi);
}

__global__ __launch_bounds__(BLOCK, 8) void NF_20581483282566_kernel(
    const float* __restrict__ x,
    const float* __restrict__ w1, const float* __restrict__ b1,
    const float* __restrict__ w2, const float* __restrict__ b2,
    const float* __restrict__ tr, const float* __restrict__ ti,
    float2* __restrict__ out, int B)
{
    __shared__ float s_r[HWIN + EPB];
    __shared__ float s_i[HWIN + EPB];

    const int t = threadIdx.x;
    const int j = t & 3;
    const long b0 = (long)blockIdx.x * EPB;

    const float4* xf4 = reinterpret_cast<const float4*>(x);
    const float4* w1v = reinterpret_cast<const float4*>(w1);
    const float4 wv0 = w1v[j];        // c=0 weights for this lane role
    const float4 wv1 = w1v[4 + j];    // c=1
    const float b1s = b1[0];
    const float b20 = b2[0], b21 = b2[1];

    if (t < 4 * EPB) {
        // ---- main elements: waves 0-14, 4 lanes per element ----
        const int e_loc = t >> 2;             // 0..239
        const long ge = b0 + e_loc;
        if (ge < B) {
            float sr, si;
            conv_elem(xf4, ge, j, wv0, wv1, b1s, w2, b20, b21, sr, si);
            if (j == 0) { s_r[HWIN + e_loc] = sr; s_i[HWIN + e_loc] = si; }
        }
    } else {
        // ---- halo: wave 15 (16 elements), loads issued concurrently ----
        const int eh = (t - 4 * EPB) >> 2;    // 0..15
        const long he = b0 - HWIN + eh;
        float sr = 0.f, si = 0.f;
        if (he >= 0)
            conv_elem(xf4, he, j, wv0, wv1, b1s, w2, b20, b21, sr, si);
        if (j == 0) { s_r[eh] = sr; s_i[eh] = si; }
    }
    __syncthreads();

    // ---- 16-tap complex FIR along the batch axis ----
    if (t < EPB) {
        const long b = b0 + t;
        if (b < B) {
            float yr = 0.f, yi = 0.f;
#pragma unroll
            for (int jj = 0; jj < TAPS; ++jj) {
                float a = s_r[HWIN + t - jj];
                float c = s_i[HWIN + t - jj];
                float trj = tr[jj], tij = ti[jj];
                yr += a * trj - c * tij;
                yi += a * tij + c * trj;
            }
            out[b] = make_float2(yr, yi);
        }
    }
}

extern "C" void kernel_launch(void* const* d_in, const int* in_sizes, int n_in,
                              void* d_out, int out_size, void* d_ws, size_t ws_size,
                              hipStream_t stream) {
    const float* x  = (const float*)d_in[0];
    const float* w1 = (const float*)d_in[1];
    const float* b1 = (const float*)d_in[2];
    const float* w2 = (const float*)d_in[3];
    const float* b2 = (const float*)d_in[4];
    const float* tr = (const float*)d_in[5];
    const float* ti = (const float*)d_in[6];
    float2* out = (float2*)d_out;

    const int B = in_sizes[0] / 128;   // x is (B, 2, 64)
    const int grid = (B + EPB - 1) / EPB;
    NF_20581483282566_kernel<<<grid, BLOCK, 0, stream>>>(x, w1, b1, w2, b2, tr, ti, out, B);
}